// Round 1
// baseline (2410.172 us; speedup 1.0000x reference)
//
#include <hip/hip_runtime.h>

#define LOG2E 1.44269504088896340736f

__device__ __forceinline__ float fexp2(float x){
#if __has_builtin(__builtin_amdgcn_exp2f)
  return __builtin_amdgcn_exp2f(x);
#else
  return __builtin_exp2f(x);
#endif
}
__device__ __forceinline__ float frcp(float x){
#if __has_builtin(__builtin_amdgcn_rcpf)
  return __builtin_amdgcn_rcpf(x);
#else
  return 1.0f/x;
#endif
}
__device__ __forceinline__ float sigmoidf_(float x){ return frcp(1.0f + fexp2(-LOG2E*x)); }
__device__ __forceinline__ float tanhf_(float x){ return 1.0f - 2.0f*frcp(1.0f + fexp2(2.0f*LOG2E*x)); }

__device__ __forceinline__ void fma4(float& acc, float4 w, float4 h){
    acc += w.x*h.x; acc += w.y*h.y; acc += w.z*h.z; acc += w.w*h.w;
}

// B=4096, I=8, T=512, H1=32, H2=16, O=1
// One wave per block; 4 sequences per wave; 16 lanes per sequence.
__global__ __launch_bounds__(64, 1)
void gru2_kernel(const float* __restrict__ x_g,
                 const float* __restrict__ Wih1, const float* __restrict__ Whh1,
                 const float* __restrict__ bih1, const float* __restrict__ bhh1,
                 const float* __restrict__ Wih2, const float* __restrict__ Whh2,
                 const float* __restrict__ bih2, const float* __restrict__ bhh2,
                 const float* __restrict__ Wlin, const float* __restrict__ blin,
                 float* __restrict__ out)
{
    const int lane = threadIdx.x;
    const int g    = lane >> 4;    // sequence-in-wave 0..3
    const int l    = lane & 15;    // role 0..15
    const int j0   = 2*l;          // layer1 hidden indices owned
    const int b    = blockIdx.x*4 + g;

    __shared__ float xsh[4][64][8];   // x chunk, transposed: [seq][t][i]
    __shared__ float h1sh[4][32];
    __shared__ float h2sh[4][16];

    // ---------------- load per-lane weights into registers ----------------
    float4 wih1[6][2];   // rows: r(j0),r(j1),z(j0),z(j1),n(j0),n(j1)  x 8 floats
    float4 whh1[6][8];   // same rows x 32 floats
    float4 wih2[3][8];   // rows: r(l),z(l),n(l) of W_ih2[48][32]
    float4 whh2[3][4];   // rows: r(l),z(l),n(l) of W_hh2[48][16]

    const float4* Wih1_4 = (const float4*)Wih1;
    const float4* Whh1_4 = (const float4*)Whh1;
    const float4* Wih2_4 = (const float4*)Wih2;
    const float4* Whh2_4 = (const float4*)Whh2;

    {
        const int rows1[6] = { j0, j0+1, 32+j0, 32+j0+1, 64+j0, 64+j0+1 };
        #pragma unroll
        for (int r = 0; r < 6; ++r) {
            const int row = rows1[r];
            wih1[r][0] = Wih1_4[row*2+0];
            wih1[r][1] = Wih1_4[row*2+1];
            #pragma unroll
            for (int c = 0; c < 8; ++c) whh1[r][c] = Whh1_4[row*8+c];
        }
        const int rows2[3] = { l, 16+l, 32+l };
        #pragma unroll
        for (int r = 0; r < 3; ++r) {
            const int row = rows2[r];
            #pragma unroll
            for (int c = 0; c < 8; ++c) wih2[r][c] = Wih2_4[row*8+c];
            #pragma unroll
            for (int c = 0; c < 4; ++c) whh2[r][c] = Whh2_4[row*4+c];
        }
    }

    // biases (r,z merged; n kept split since b_hh_n sits inside r*(...))
    const float br0  = bih1[j0]      + bhh1[j0];
    const float br1  = bih1[j0+1]    + bhh1[j0+1];
    const float bz0  = bih1[32+j0]   + bhh1[32+j0];
    const float bz1  = bih1[32+j0+1] + bhh1[32+j0+1];
    const float bnx0 = bih1[64+j0];
    const float bnx1 = bih1[64+j0+1];
    const float bnh0 = bhh1[64+j0];
    const float bnh1 = bhh1[64+j0+1];

    const float b2r  = bih2[l]    + bhh2[l];
    const float b2z  = bih2[16+l] + bhh2[16+l];
    const float b2nx = bih2[32+l];
    const float b2nh = bhh2[32+l];

    // ---------------- state ----------------
    float4 h1r[8], h2r[4];
    #pragma unroll
    for (int k = 0; k < 8; ++k) h1r[k] = make_float4(0.f,0.f,0.f,0.f);
    #pragma unroll
    for (int k = 0; k < 4; ++k) h2r[k] = make_float4(0.f,0.f,0.f,0.f);
    float hz0 = 0.f, hz1 = 0.f, hz2 = 0.f;

    const float4* in4 = (const float4*)x_g;
    const int sub = lane >> 4;
    const int t4  = (lane & 15) * 4;

    for (int tc = 0; tc < 8; ++tc) {
        const int t0 = tc * 64;
        // ---- stage x chunk: global [b][i][t] -> LDS [g][t][i] ----
        #pragma unroll
        for (int it = 0; it < 8; ++it) {
            const int R  = it*4 + sub;      // 0..31 = (gi,ii)
            const int gi = R >> 3, ii = R & 7;
            const int bb = blockIdx.x*4 + gi;
            const float4 v = in4[bb*1024 + ii*128 + ((t0 + t4) >> 2)];
            xsh[gi][t4+0][ii] = v.x;
            xsh[gi][t4+1][ii] = v.y;
            xsh[gi][t4+2][ii] = v.z;
            xsh[gi][t4+3][ii] = v.w;
        }
        // single wave per block: DS ops are in-order, no barrier needed

        #pragma unroll 2
        for (int tt = 0; tt < 64; ++tt) {
            const float4 xa = *(const float4*)&xsh[g][tt][0];
            const float4 xb = *(const float4*)&xsh[g][tt][4];

            // -------- layer 1: gates for j0, j0+1 --------
            float ar0 = br0, ar1 = br1, az0 = bz0, az1 = bz1;
            float anx0 = bnx0, anx1 = bnx1, gn0 = bnh0, gn1 = bnh1;

            fma4(ar0,  wih1[0][0], xa); fma4(ar0,  wih1[0][1], xb);
            fma4(ar1,  wih1[1][0], xa); fma4(ar1,  wih1[1][1], xb);
            fma4(az0,  wih1[2][0], xa); fma4(az0,  wih1[2][1], xb);
            fma4(az1,  wih1[3][0], xa); fma4(az1,  wih1[3][1], xb);
            fma4(anx0, wih1[4][0], xa); fma4(anx0, wih1[4][1], xb);
            fma4(anx1, wih1[5][0], xa); fma4(anx1, wih1[5][1], xb);

            #pragma unroll
            for (int k = 0; k < 8; ++k) {
                fma4(ar0, whh1[0][k], h1r[k]);
                fma4(ar1, whh1[1][k], h1r[k]);
                fma4(az0, whh1[2][k], h1r[k]);
                fma4(az1, whh1[3][k], h1r[k]);
                fma4(gn0, whh1[4][k], h1r[k]);
                fma4(gn1, whh1[5][k], h1r[k]);
            }

            const float r0 = sigmoidf_(ar0), r1 = sigmoidf_(ar1);
            const float z0 = sigmoidf_(az0), z1 = sigmoidf_(az1);
            const float n0 = tanhf_(anx0 + r0*gn0);
            const float n1 = tanhf_(anx1 + r1*gn1);
            const float h0 = n0 + z0*(hz0 - n0);
            const float h1 = n1 + z1*(hz1 - n1);
            hz0 = h0; hz1 = h1;

            *(float2*)&h1sh[g][j0] = make_float2(h0, h1);
            #pragma unroll
            for (int k = 0; k < 8; ++k) h1r[k] = *(const float4*)&h1sh[g][4*k];

            // -------- layer 2: gates for index l --------
            float a2r = b2r, a2z = b2z, a2nx = b2nx, g2n = b2nh;
            #pragma unroll
            for (int k = 0; k < 8; ++k) {
                fma4(a2r,  wih2[0][k], h1r[k]);
                fma4(a2z,  wih2[1][k], h1r[k]);
                fma4(a2nx, wih2[2][k], h1r[k]);
            }
            #pragma unroll
            for (int k = 0; k < 4; ++k) {
                fma4(a2r, whh2[0][k], h2r[k]);
                fma4(a2z, whh2[1][k], h2r[k]);
                fma4(g2n, whh2[2][k], h2r[k]);
            }
            const float r2 = sigmoidf_(a2r), z2 = sigmoidf_(a2z);
            const float n2 = tanhf_(a2nx + r2*g2n);
            const float h2 = n2 + z2*(hz2 - n2);
            hz2 = h2;

            h2sh[g][l] = h2;
            #pragma unroll
            for (int k = 0; k < 4; ++k) h2r[k] = *(const float4*)&h2sh[g][4*k];
        }
    }

    // -------- linear head on last h2 --------
    if (l == 0) {
        float acc = blin[0];
        const float4* Wl4 = (const float4*)Wlin;
        #pragma unroll
        for (int k = 0; k < 4; ++k) fma4(acc, Wl4[k], h2r[k]);
        out[b] = acc;
    }
}

extern "C" void kernel_launch(void* const* d_in, const int* in_sizes, int n_in,
                              void* d_out, int out_size, void* d_ws, size_t ws_size,
                              hipStream_t stream) {
    const float* x    = (const float*)d_in[0];
    const float* Wih1 = (const float*)d_in[1];
    const float* Whh1 = (const float*)d_in[2];
    const float* bih1 = (const float*)d_in[3];
    const float* bhh1 = (const float*)d_in[4];
    const float* Wih2 = (const float*)d_in[5];
    const float* Whh2 = (const float*)d_in[6];
    const float* bih2 = (const float*)d_in[7];
    const float* bhh2 = (const float*)d_in[8];
    const float* Wlin = (const float*)d_in[9];
    const float* blin = (const float*)d_in[10];
    float* out = (float*)d_out;

    dim3 grid(1024), block(64);
    hipLaunchKernelGGL(gru2_kernel, grid, block, 0, stream,
                       x, Wih1, Whh1, bih1, bhh1, Wih2, Whh2, bih2, bhh2,
                       Wlin, blin, out);
}

// Round 2
// 731.452 us; speedup vs baseline: 3.2951x; 3.2951x over previous
//
#include <hip/hip_runtime.h>

#define LOG2E 1.44269504088896340736f

__device__ __forceinline__ float fexp2(float x){ return __builtin_amdgcn_exp2f(x); }
__device__ __forceinline__ float frcp(float x){ return __builtin_amdgcn_rcpf(x); }
__device__ __forceinline__ float sigmoidf_(float x){ return frcp(1.0f + fexp2(-LOG2E*x)); }
__device__ __forceinline__ float tanhf_(float x){ return 1.0f - 2.0f*frcp(1.0f + fexp2(2.0f*LOG2E*x)); }
__device__ __forceinline__ float d4(float4 w, float4 v){
    return fmaf(w.x,v.x, fmaf(w.y,v.y, fmaf(w.z,v.z, w.w*v.w)));
}

// B=4096, I=8, T=512, H1=32, H2=16, O=1
// One wave per block, one sequence per wave.
// Layer1: 32 units x 2 lanes (20-col slices of [x(8);h1(32)]).
// Layer2: 16 units x 4 lanes (12-col slices of [h1(32);h2(16)]).
__global__ __launch_bounds__(64, 2)
void gru2_kernel(const float* __restrict__ x_g,
                 const float* __restrict__ Wih1, const float* __restrict__ Whh1,
                 const float* __restrict__ bih1, const float* __restrict__ bhh1,
                 const float* __restrict__ Wih2, const float* __restrict__ Whh2,
                 const float* __restrict__ bih2, const float* __restrict__ bhh2,
                 const float* __restrict__ Wlin, const float* __restrict__ blin,
                 float* __restrict__ out)
{
    const int lane = threadIdx.x;
    const int b    = blockIdx.x;
    const int j    = lane >> 1;   // layer1 unit 0..31
    const int half = lane & 1;    // column-half
    const int u    = lane >> 2;   // layer2 unit 0..15
    const int q    = lane & 3;    // column-quarter

    __shared__ float xsh[64][8];  // x chunk [t][i]
    __shared__ float hbuf[48];    // [h1(32); h2(16)]

    if (lane < 48) hbuf[lane] = 0.0f;

    // ---------------- per-lane weights (96 floats) ----------------
    float4 w1[15];  // 3 gates x 5 float4 (20-col slice of [x|h1])
    {
        const float4* Wih1_4 = (const float4*)Wih1;   // row stride 2
        const float4* Whh1_4 = (const float4*)Whh1;   // row stride 8
        #pragma unroll
        for (int g = 0; g < 3; ++g) {
            const int row = g*32 + j;
            if (half == 0) {
                w1[g*5+0] = Wih1_4[row*2+0];
                w1[g*5+1] = Wih1_4[row*2+1];
                w1[g*5+2] = Whh1_4[row*8+0];
                w1[g*5+3] = Whh1_4[row*8+1];
                w1[g*5+4] = Whh1_4[row*8+2];
            } else {
                #pragma unroll
                for (int k = 0; k < 5; ++k) w1[g*5+k] = Whh1_4[row*8+3+k];
            }
        }
    }
    float4 w2[9];   // 3 gates x 3 float4 (12-col slice of [h1|h2])
    {
        const float4* Wih2_4 = (const float4*)Wih2;   // row stride 8
        const float4* Whh2_4 = (const float4*)Whh2;   // row stride 4
        #pragma unroll
        for (int g = 0; g < 3; ++g) {
            const int row = g*16 + u;
            #pragma unroll
            for (int k = 0; k < 3; ++k) {
                const int col4 = q*3 + k;              // float4 group in 48-col space
                const float4* p = (col4 < 8) ? (Wih2_4 + row*8 + col4)
                                             : (Whh2_4 + row*4 + (col4 - 8));
                w2[g*3+k] = *p;
            }
        }
    }

    // biases
    const float br1_  = bih1[j]      + bhh1[j];
    const float bz1_  = bih1[32+j]   + bhh1[32+j];
    const float bnx1_ = bih1[64+j];
    const float bnh1_ = bhh1[64+j];
    const float br2_  = bih2[u]      + bhh2[u];
    const float bz2_  = bih2[16+u]   + bhh2[16+u];
    const float bnx2_ = bih2[32+u];
    const float bnh2_ = bhh2[32+u];

    float h1p = 0.f, h2p = 0.f;   // owned hidden values (replicated in lane group)

    // per-lane slice pointers (constant except x advances with t)
    const float4* const baseA0 = (const float4*)&xsh[0][0];
    const float4* const baseA1 = (const float4*)&hbuf[12];
    const float4* const pB1    = (const float4*)(half==0 ? &hbuf[0] : &hbuf[20]);
    const float4* const pC     = (const float4*)&hbuf[q*12];
    const int incA = (half==0) ? 2 : 0;   // advance 32B/step only for x readers

    const float* xb = x_g + (size_t)b * 4096;   // 8*512

    for (int tc = 0; tc < 8; ++tc) {
        // ---- stage 64-step x chunk: global [i][t] -> LDS [t][i] ----
        #pragma unroll
        for (int k = 0; k < 8; ++k) {
            xsh[lane][k] = xb[k*512 + tc*64 + lane];
        }
        const float4* pA = (half==0) ? baseA0 : baseA1;

        for (int tt = 0; tt < 64; ++tt) {
            // -------- layer 1 --------
            const float4 v0 = pA[0], v1 = pA[1];
            const float4 v2 = pB1[0], v3 = pB1[1], v4 = pB1[2];
            pA += incA;

            float ar = ((d4(w1[0],v0)+d4(w1[1],v1)) + (d4(w1[2],v2)+d4(w1[3],v3))) + d4(w1[4],v4);
            float az = ((d4(w1[5],v0)+d4(w1[6],v1)) + (d4(w1[7],v2)+d4(w1[8],v3))) + d4(w1[9],v4);
            const float pAs = d4(w1[10],v0) + d4(w1[11],v1);
            const float pBs = (d4(w1[12],v2)+d4(w1[13],v3)) + d4(w1[14],v4);
            float anx = (half==0) ? pAs : 0.0f;
            float anh = (half==0) ? pBs : (pAs + pBs);

            ar  += __shfl_xor(ar, 1, 64);
            az  += __shfl_xor(az, 1, 64);
            anx += __shfl_xor(anx,1, 64);
            anh += __shfl_xor(anh,1, 64);

            const float r  = sigmoidf_(ar + br1_);
            const float z  = sigmoidf_(az + bz1_);
            const float n  = tanhf_(anx + bnx1_ + r*(anh + bnh1_));
            const float h1n = n + z*(h1p - n);
            h1p = h1n;
            if (half == 0) hbuf[j] = h1n;

            // -------- layer 2 --------
            const float4 u0 = pC[0], u1 = pC[1], u2 = pC[2];
            float a2r = (d4(w2[0],u0)+d4(w2[1],u1)) + d4(w2[2],u2);
            float a2z = (d4(w2[3],u0)+d4(w2[4],u1)) + d4(w2[5],u2);
            const float s0 = d4(w2[6],u0), s1 = d4(w2[7],u1), s2 = d4(w2[8],u2);
            const float s01 = s0 + s1, sall = s01 + s2;
            float a2nx = (q < 2) ? sall : ((q == 2) ? s01 : 0.0f);
            float a2nh = (q < 2) ? 0.0f : ((q == 2) ? s2  : sall);

            a2r  += __shfl_xor(a2r, 1, 64);  a2r  += __shfl_xor(a2r, 2, 64);
            a2z  += __shfl_xor(a2z, 1, 64);  a2z  += __shfl_xor(a2z, 2, 64);
            a2nx += __shfl_xor(a2nx,1, 64);  a2nx += __shfl_xor(a2nx,2, 64);
            a2nh += __shfl_xor(a2nh,1, 64);  a2nh += __shfl_xor(a2nh,2, 64);

            const float r2 = sigmoidf_(a2r + br2_);
            const float z2 = sigmoidf_(a2z + bz2_);
            const float n2 = tanhf_(a2nx + bnx2_ + r2*(a2nh + bnh2_));
            const float h2n = n2 + z2*(h2p - n2);
            h2p = h2n;
            if (q == 0) hbuf[32+u] = h2n;
        }
    }

    // -------- linear head on final h2 --------
    if (lane == 0) {
        const float4* hb = (const float4*)&hbuf[32];
        const float4* Wl = (const float4*)Wlin;
        float acc = blin[0];
        #pragma unroll
        for (int k = 0; k < 4; ++k) acc += d4(Wl[k], hb[k]);
        out[b] = acc;
    }
}

extern "C" void kernel_launch(void* const* d_in, const int* in_sizes, int n_in,
                              void* d_out, int out_size, void* d_ws, size_t ws_size,
                              hipStream_t stream) {
    const float* x    = (const float*)d_in[0];
    const float* Wih1 = (const float*)d_in[1];
    const float* Whh1 = (const float*)d_in[2];
    const float* bih1 = (const float*)d_in[3];
    const float* bhh1 = (const float*)d_in[4];
    const float* Wih2 = (const float*)d_in[5];
    const float* Whh2 = (const float*)d_in[6];
    const float* bih2 = (const float*)d_in[7];
    const float* bhh2 = (const float*)d_in[8];
    const float* Wlin = (const float*)d_in[9];
    const float* blin = (const float*)d_in[10];
    float* out = (float*)d_out;

    dim3 grid(4096), block(64);
    hipLaunchKernelGGL(gru2_kernel, grid, block, 0, stream,
                       x, Wih1, Whh1, bih1, bhh1, Wih2, Whh2, bih2, bhh2,
                       Wlin, blin, out);
}

// Round 3
// 451.536 us; speedup vs baseline: 5.3377x; 1.6199x over previous
//
#include <hip/hip_runtime.h>

#define LOG2E 1.44269504088896340736f

__device__ __forceinline__ float fexp2(float x){ return __builtin_amdgcn_exp2f(x); }
__device__ __forceinline__ float frcp(float x){ return __builtin_amdgcn_rcpf(x); }
__device__ __forceinline__ float sigmoidf_(float x){ return frcp(1.0f + fexp2(-LOG2E*x)); }
__device__ __forceinline__ float tanhf_(float x){ return 1.0f - 2.0f*frcp(1.0f + fexp2(2.0f*LOG2E*x)); }

__device__ __forceinline__ void acc4(float& a, float4 w, float4 v){
    a = fmaf(w.x, v.x, a); a = fmaf(w.y, v.y, a);
    a = fmaf(w.z, v.z, a); a = fmaf(w.w, v.w, a);
}
// add value from lane^1 (quad_perm [1,0,3,2]) — pure VALU, no LDS
__device__ __forceinline__ float xor1_add(float x){
    int y = __builtin_amdgcn_update_dpp(0, __builtin_bit_cast(int, x), 0xB1, 0xF, 0xF, true);
    return x + __builtin_bit_cast(float, y);
}

// B=4096, I=8, T=512, H1=32, H2=16, O=1
// 2 sequences per wave (seq-half s = lane>>5).
// Layer1: 1 lane per unit (32 units), full 40-col x 3-gate dots, no reduce.
// Layer2: 2 lanes per unit (24-col halves), 1 DPP xor1 reduce per value.
__global__ __launch_bounds__(256, 2)
void gru2_kernel(const float* __restrict__ x_g,
                 const float* __restrict__ Wih1, const float* __restrict__ Whh1,
                 const float* __restrict__ bih1, const float* __restrict__ bhh1,
                 const float* __restrict__ Wih2, const float* __restrict__ Whh2,
                 const float* __restrict__ bih2, const float* __restrict__ bhh2,
                 const float* __restrict__ Wlin, const float* __restrict__ blin,
                 float* __restrict__ out)
{
    const int tid  = threadIdx.x;
    const int wid  = tid >> 6;
    const int lane = tid & 63;
    const int s    = lane >> 5;   // seq within wave
    const int sl   = lane & 31;
    const int j    = sl;          // layer1 unit
    const int u    = sl >> 1;     // layer2 unit
    const int c    = sl & 1;      // layer2 column half
    const int b    = blockIdx.x*8 + wid*2 + s;

    __shared__ float xsh[4][2][32][12];  // [wave][seq][t][i(pad12)]
    __shared__ float hbuf[4][2][48];     // [wave][seq][h1(32);h2(16)]

    {   // zero own wave's h buffers (wave-private, no barrier needed)
        float* hb = &hbuf[wid][0][0];
        for (int i = lane; i < 96; i += 64) hb[i] = 0.0f;
    }

    // ---------------- per-lane weights ----------------
    const float4* Wih1_4 = (const float4*)Wih1;   // [96][2]
    const float4* Whh1_4 = (const float4*)Whh1;   // [96][8]
    const float4* Wih2_4 = (const float4*)Wih2;   // [48][8]
    const float4* Whh2_4 = (const float4*)Whh2;   // [48][4]

    float4 w1x[3][2];   // layer1: x part (8 cols)
    float4 w1h[3][8];   // layer1: h part (32 cols)
    #pragma unroll
    for (int g = 0; g < 3; ++g) {
        const int row = g*32 + j;
        w1x[g][0] = Wih1_4[row*2+0];
        w1x[g][1] = Wih1_4[row*2+1];
        #pragma unroll
        for (int k = 0; k < 8; ++k) w1h[g][k] = Whh1_4[row*8+k];
    }
    float4 w2[3][6];    // layer2: 24-col slice of [h1(32);h2(16)]
    #pragma unroll
    for (int g = 0; g < 3; ++g) {
        const int row = g*16 + u;
        if (c == 0) {
            #pragma unroll
            for (int k = 0; k < 6; ++k) w2[g][k] = Wih2_4[row*8+k];
        } else {
            w2[g][0] = Wih2_4[row*8+6];
            w2[g][1] = Wih2_4[row*8+7];
            #pragma unroll
            for (int k = 0; k < 4; ++k) w2[g][2+k] = Whh2_4[row*4+k];
        }
    }

    // biases
    const float b1r  = bih1[j]      + bhh1[j];
    const float b1z  = bih1[32+j]   + bhh1[32+j];
    const float b1nx = bih1[64+j];
    const float b1nh = bhh1[64+j];
    const float b2r  = bih2[u]      + bhh2[u];
    const float b2z  = bih2[16+u]   + bhh2[16+u];
    const float b2nx = bih2[32+u];
    const float b2nh = bhh2[32+u];

    float h1p = 0.0f, h2p = 0.0f;

    const float*  xg  = x_g + (size_t)b * 4096;       // [8][512]
    const float4* hb4 = (const float4*)&hbuf[wid][s][0];
    const float4* cb4 = (const float4*)&hbuf[wid][s][c*24];
    float* const  h1w = &hbuf[wid][s][j];
    float* const  h2w = &hbuf[wid][s][32+u];

    for (int tc = 0; tc < 16; ++tc) {
        // stage 32 timesteps: global [i][t] -> LDS [t][i]
        #pragma unroll
        for (int k = 0; k < 8; ++k)
            xsh[wid][s][sl][k] = xg[k*512 + tc*32 + sl];

        #pragma unroll 1
        for (int tt = 0; tt < 32; ++tt) {
            // -------- layer 1 (unit j, full row) --------
            const float4 xa = *(const float4*)&xsh[wid][s][tt][0];
            const float4 xb = *(const float4*)&xsh[wid][s][tt][4];

            float ar = b1r, az = b1z, ax = b1nx, ah = b1nh;
            acc4(ar, w1x[0][0], xa); acc4(ar, w1x[0][1], xb);
            acc4(az, w1x[1][0], xa); acc4(az, w1x[1][1], xb);
            acc4(ax, w1x[2][0], xa); acc4(ax, w1x[2][1], xb);
            #pragma unroll
            for (int k = 0; k < 8; ++k) {
                const float4 v = hb4[k];
                acc4(ar, w1h[0][k], v);
                acc4(az, w1h[1][k], v);
                acc4(ah, w1h[2][k], v);
            }
            const float r  = sigmoidf_(ar);
            const float z  = sigmoidf_(az);
            const float n  = tanhf_(fmaf(r, ah, ax));
            const float h1n = n + z*(h1p - n);
            h1p = h1n;
            *h1w = h1n;                      // ds_write, in-order before reads below

            // -------- layer 2 (unit u, column half c) --------
            float a2r = 0.f, a2z = 0.f, sA = 0.f, sB = 0.f;
            {
                const float4 u0 = cb4[0], u1 = cb4[1], u2 = cb4[2];
                const float4 u3 = cb4[3], u4 = cb4[4], u5 = cb4[5];
                acc4(a2r, w2[0][0], u0); acc4(a2r, w2[0][1], u1); acc4(a2r, w2[0][2], u2);
                acc4(a2r, w2[0][3], u3); acc4(a2r, w2[0][4], u4); acc4(a2r, w2[0][5], u5);
                acc4(a2z, w2[1][0], u0); acc4(a2z, w2[1][1], u1); acc4(a2z, w2[1][2], u2);
                acc4(a2z, w2[1][3], u3); acc4(a2z, w2[1][4], u4); acc4(a2z, w2[1][5], u5);
                acc4(sA,  w2[2][0], u0); acc4(sA,  w2[2][1], u1);
                acc4(sB,  w2[2][2], u2); acc4(sB,  w2[2][3], u3);
                acc4(sB,  w2[2][4], u4); acc4(sB,  w2[2][5], u5);
            }
            // c==0: all 24 cols are n_x;  c==1: first 8 are n_x, last 16 are n_h
            float sx = (c == 0) ? (sA + sB) : sA;
            float sh = (c == 0) ? 0.0f      : sB;

            const float t2r = xor1_add(a2r);
            const float t2z = xor1_add(a2z);
            sx = xor1_add(sx);
            sh = xor1_add(sh);

            const float r2 = sigmoidf_(t2r + b2r);
            const float z2 = sigmoidf_(t2z + b2z);
            const float n2 = tanhf_(sx + b2nx + r2*(sh + b2nh));
            const float h2n = n2 + z2*(h2p - n2);
            h2p = h2n;
            if (c == 0) *h2w = h2n;
        }
    }

    // -------- linear head on final h2 --------
    if (sl == 0) {
        const float4* h2v = (const float4*)&hbuf[wid][s][32];
        const float4* Wl4 = (const float4*)Wlin;
        float acc = blin[0];
        #pragma unroll
        for (int k = 0; k < 4; ++k) acc4(acc, Wl4[k], h2v[k]);
        out[b] = acc;
    }
}

extern "C" void kernel_launch(void* const* d_in, const int* in_sizes, int n_in,
                              void* d_out, int out_size, void* d_ws, size_t ws_size,
                              hipStream_t stream) {
    const float* x    = (const float*)d_in[0];
    const float* Wih1 = (const float*)d_in[1];
    const float* Whh1 = (const float*)d_in[2];
    const float* bih1 = (const float*)d_in[3];
    const float* bhh1 = (const float*)d_in[4];
    const float* Wih2 = (const float*)d_in[5];
    const float* Whh2 = (const float*)d_in[6];
    const float* bih2 = (const float*)d_in[7];
    const float* bhh2 = (const float*)d_in[8];
    const float* Wlin = (const float*)d_in[9];
    const float* blin = (const float*)d_in[10];
    float* out = (float*)d_out;

    dim3 grid(512), block(256);
    hipLaunchKernelGGL(gru2_kernel, grid, block, 0, stream,
                       x, Wih1, Whh1, bih1, bhh1, Wih2, Whh2, bih2, bhh2,
                       Wlin, blin, out);
}

// Round 4
// 260.194 us; speedup vs baseline: 9.2630x; 1.7354x over previous
//
#include <hip/hip_runtime.h>

typedef __attribute__((ext_vector_type(4))) float    f32x4;
typedef __attribute__((ext_vector_type(4))) unsigned u32x4;

#define LOG2E 1.44269504088896340736f
__device__ __forceinline__ float fexp2(float x){ return __builtin_amdgcn_exp2f(x); }
__device__ __forceinline__ float frcp (float x){ return __builtin_amdgcn_rcpf(x); }
__device__ __forceinline__ float sigf (float x){ return frcp(1.0f + fexp2(-LOG2E*x)); }
__device__ __forceinline__ float tanh_(float x){ return 1.0f - 2.0f*frcp(1.0f + fexp2(2.0f*LOG2E*x)); }

// round-to-nearest-even fp32 -> bf16 (low 16 bits of result)
__device__ __forceinline__ unsigned rne_bf16(float f){
    unsigned u = __builtin_bit_cast(unsigned, f);
    return (u + 0x7fffu + ((u >> 16) & 1u)) >> 16;
}
// weight word: same bf16 in both halves (multiplies hi and lo slots of v)
__device__ __forceinline__ u32x4 packdup4(const float* p){
    u32x4 r;
    #pragma unroll
    for (int q = 0; q < 4; ++q) {
        unsigned w = rne_bf16(p[q]);
        r[q] = w | (w << 16);
    }
    return r;
}
// value word: lo half = bf16_trunc(h) [k even], hi half = bf16_trunc(h - hi) [k odd]
__device__ __forceinline__ unsigned packsplit(float h){
    unsigned hu = __builtin_bit_cast(unsigned, h);
    unsigned hm = hu & 0xffff0000u;
    float rem = h - __builtin_bit_cast(float, hm);
    unsigned ru = __builtin_bit_cast(unsigned, rem);
    return (hm >> 16) | (ru & 0xffff0000u);
}

// D[m=gate16][n=seq16] += A[m][k] * B[k][n], K=32.  Inline asm: avoids builtin
// signature ambiguity; k-mapping errors cancel (A and B built with same map).
#define MFMA_INIT(d, a, b, c) asm("v_mfma_f32_16x16x32_bf16 %0, %1, %2, %3" : "=&v"(d) : "v"(a), "v"(b), "v"(c))
#define MFMA_ACC(acc, a, b)   asm("v_mfma_f32_16x16x32_bf16 %0, %1, %2, %0" : "+v"(acc) : "v"(a), "v"(b))

// B=4096, I=8, T=512, H1=32, H2=16, O=1.
// 16 seqs per block, 3 waves: w0/w1 = layer1 units 0..15 / 16..31, w2 = layer2
// (lagging one step). 1 barrier per step; h1/h2 double-buffered in LDS.
__global__ __launch_bounds__(192)
void gru2_mfma(const float* __restrict__ x_g,
               const float* __restrict__ Wih1, const float* __restrict__ Whh1,
               const float* __restrict__ bih1, const float* __restrict__ bhh1,
               const float* __restrict__ Wih2, const float* __restrict__ Whh2,
               const float* __restrict__ bih2, const float* __restrict__ bhh2,
               const float* __restrict__ Wlin, const float* __restrict__ blin,
               float* __restrict__ out)
{
    const int tid = threadIdx.x;
    const int wid = tid / 64;
    const int l   = tid & 63;
    const int sl  = l & 15;   // seq index (B col / C col); also A row (gate)
    const int g   = l >> 4;   // k-group (k = 8g..8g+7 -> 4 value-words 4g..4g+3)
    const int b0  = blockIdx.x * 16;

    __shared__ unsigned xpk[32][16][12];  // [t][seq][8 x-words + pad4]
    __shared__ unsigned h1b[2][16][36];   // [par][seq][32 unit-words + pad4]
    __shared__ unsigned h2b[2][16][20];   // [par][seq][16 unit-words + pad4]
    __shared__ unsigned zl[4];            // 16B of zeros for T0 k>=16

    {   // zero-init state buffers
        unsigned* p1 = &h1b[0][0][0];
        for (int k = tid; k < 2*16*36; k += 192) p1[k] = 0u;
        unsigned* p2 = &h2b[0][0][0];
        for (int k = tid; k < 2*16*20; k += 192) p2[k] = 0u;
        if (tid < 4) zl[tid] = 0u;
    }

    // ---------------- per-role weight + bias fragments ----------------
    u32x4 fR0, fR1, fR2, fZ0, fZ1, fZ2, fX0, fA, fB;
    f32x4 cbR, cbZ, cbX, cbH;
    const u32x4 zero4 = {0u, 0u, 0u, 0u};

    if (wid < 2) {
        const int Ub = wid * 16;
        const int gr = Ub + sl, gz = 32 + Ub + sl, gn = 64 + Ub + sl;
        fR0 = (g < 2) ? packdup4(Wih1 + gr*8  + 4*g) : zero4;  // T0: x cols
        fR1 = packdup4(Whh1 + gr*32 + 4*g);                    // T1: h1 cols 0..15
        fR2 = packdup4(Whh1 + gr*32 + 16 + 4*g);               // T2: h1 cols 16..31
        fZ0 = (g < 2) ? packdup4(Wih1 + gz*8  + 4*g) : zero4;
        fZ1 = packdup4(Whh1 + gz*32 + 4*g);
        fZ2 = packdup4(Whh1 + gz*32 + 16 + 4*g);
        fX0 = (g < 2) ? packdup4(Wih1 + gn*8  + 4*g) : zero4;  // nx: x part only
        fA  = packdup4(Whh1 + gn*32 + 4*g);                    // nh: h part
        fB  = packdup4(Whh1 + gn*32 + 16 + 4*g);
        #pragma unroll
        for (int e = 0; e < 4; ++e) {
            const int u = Ub + 4*g + e;   // C row = unit
            cbR[e] = bih1[u]      + bhh1[u];
            cbZ[e] = bih1[32+u]   + bhh1[32+u];
            cbX[e] = bih1[64+u];
            cbH[e] = bhh1[64+u];
        }
    } else {
        fR0 = packdup4(Wih2 + sl*32 + 4*g);           // U0: h1 cols 0..15
        fR1 = packdup4(Wih2 + sl*32 + 16 + 4*g);      // U1: h1 cols 16..31
        fR2 = packdup4(Whh2 + sl*16 + 4*g);           // U2: h2 cols 0..15
        fZ0 = packdup4(Wih2 + (16+sl)*32 + 4*g);
        fZ1 = packdup4(Wih2 + (16+sl)*32 + 16 + 4*g);
        fZ2 = packdup4(Whh2 + (16+sl)*16 + 4*g);
        fX0 = packdup4(Wih2 + (32+sl)*32 + 4*g);      // nx2: h1 part
        fA  = packdup4(Wih2 + (32+sl)*32 + 16 + 4*g);
        fB  = packdup4(Whh2 + (32+sl)*16 + 4*g);      // nh2: h2 part
        #pragma unroll
        for (int e = 0; e < 4; ++e) {
            const int u = 4*g + e;
            cbR[e] = bih2[u]    + bhh2[u];
            cbZ[e] = bih2[16+u] + bhh2[16+u];
            cbX[e] = bih2[32+u];
            cbH[e] = bhh2[32+u];
        }
    }

    float hv[4] = {0.f, 0.f, 0.f, 0.f};  // w0/w1: h1 old; w2: h2 old

    #pragma unroll 1
    for (int i = 0; i <= 512; ++i) {
        if ((i & 31) == 0 && i < 512) {
            // stage 32 timesteps of x, pre-split to bf16 hi/lo words
            if (tid < 128) {
                const int s  = tid >> 3;
                const int ii = tid & 7;
                const float* xg = x_g + ((size_t)(b0 + s))*4096 + ii*512 + i;
                #pragma unroll
                for (int w4 = 0; w4 < 8; ++w4) {
                    const f32x4 v = *(const f32x4*)(xg + 4*w4);
                    #pragma unroll
                    for (int e = 0; e < 4; ++e)
                        xpk[w4*4 + e][s][ii] = packsplit(v[e]);
                }
            }
            __syncthreads();
        }

        const int pr = (i + 1) & 1;   // parity holding h1(i-1)

        if (wid < 2 && i < 512) {
            const int tt = i & 31;
            const u32x4 bT0 = (g < 2) ? *(const u32x4*)&xpk[tt][sl][4*g]
                                      : *(const u32x4*)&zl[0];
            const u32x4 bT1 = *(const u32x4*)&h1b[pr][sl][4*g];
            const u32x4 bT2 = *(const u32x4*)&h1b[pr][sl][16 + 4*g];
            f32x4 cr, cz, cx, cn;
            MFMA_INIT(cr, fR0, bT0, cbR); MFMA_ACC(cr, fR1, bT1); MFMA_ACC(cr, fR2, bT2);
            MFMA_INIT(cz, fZ0, bT0, cbZ); MFMA_ACC(cz, fZ1, bT1); MFMA_ACC(cz, fZ2, bT2);
            MFMA_INIT(cx, fX0, bT0, cbX);
            MFMA_INIT(cn, fA,  bT1, cbH); MFMA_ACC(cn, fB, bT2);
            unsigned wr0, wr1, wr2, wr3;
            {
                float r, z, n, h;
                r = sigf(cr[0]); z = sigf(cz[0]); n = tanh_(fmaf(r, cn[0], cx[0]));
                h = n + z*(hv[0]-n); hv[0] = h; wr0 = packsplit(h);
                r = sigf(cr[1]); z = sigf(cz[1]); n = tanh_(fmaf(r, cn[1], cx[1]));
                h = n + z*(hv[1]-n); hv[1] = h; wr1 = packsplit(h);
                r = sigf(cr[2]); z = sigf(cz[2]); n = tanh_(fmaf(r, cn[2], cx[2]));
                h = n + z*(hv[2]-n); hv[2] = h; wr2 = packsplit(h);
                r = sigf(cr[3]); z = sigf(cz[3]); n = tanh_(fmaf(r, cn[3], cx[3]));
                h = n + z*(hv[3]-n); hv[3] = h; wr3 = packsplit(h);
            }
            u32x4 wv = {wr0, wr1, wr2, wr3};
            *(u32x4*)&h1b[i & 1][sl][(wid ? 16 : 0) + 4*g] = wv;
        }

        if (wid == 2 && i > 0) {
            const u32x4 bU0 = *(const u32x4*)&h1b[pr][sl][4*g];
            const u32x4 bU1 = *(const u32x4*)&h1b[pr][sl][16 + 4*g];
            const u32x4 bU2 = *(const u32x4*)&h2b[i & 1][sl][4*g];
            f32x4 cr, cz, cx, cn;
            MFMA_INIT(cr, fR0, bU0, cbR); MFMA_ACC(cr, fR1, bU1); MFMA_ACC(cr, fR2, bU2);
            MFMA_INIT(cz, fZ0, bU0, cbZ); MFMA_ACC(cz, fZ1, bU1); MFMA_ACC(cz, fZ2, bU2);
            MFMA_INIT(cx, fX0, bU0, cbX); MFMA_ACC(cx, fA, bU1);
            MFMA_INIT(cn, fB,  bU2, cbH);
            unsigned wr0, wr1, wr2, wr3;
            {
                float r, z, n, h;
                r = sigf(cr[0]); z = sigf(cz[0]); n = tanh_(fmaf(r, cn[0], cx[0]));
                h = n + z*(hv[0]-n); hv[0] = h; wr0 = packsplit(h);
                r = sigf(cr[1]); z = sigf(cz[1]); n = tanh_(fmaf(r, cn[1], cx[1]));
                h = n + z*(hv[1]-n); hv[1] = h; wr1 = packsplit(h);
                r = sigf(cr[2]); z = sigf(cz[2]); n = tanh_(fmaf(r, cn[2], cx[2]));
                h = n + z*(hv[2]-n); hv[2] = h; wr2 = packsplit(h);
                r = sigf(cr[3]); z = sigf(cz[3]); n = tanh_(fmaf(r, cn[3], cx[3]));
                h = n + z*(hv[3]-n); hv[3] = h; wr3 = packsplit(h);
            }
            u32x4 wv = {wr0, wr1, wr2, wr3};
            *(u32x4*)&h2b[(i + 1) & 1][sl][4*g] = wv;   // h2(i-1)
        }

        __syncthreads();
    }

    // -------- linear head: w2's hv = fp32 h2(T-1) for units 4g..4g+3 --------
    if (wid == 2) {
        float acc = 0.0f;
        acc = fmaf(Wlin[4*g+0], hv[0], acc);
        acc = fmaf(Wlin[4*g+1], hv[1], acc);
        acc = fmaf(Wlin[4*g+2], hv[2], acc);
        acc = fmaf(Wlin[4*g+3], hv[3], acc);
        acc += __shfl_xor(acc, 16, 64);
        acc += __shfl_xor(acc, 32, 64);
        if (g == 0) out[b0 + sl] = acc + blin[0];
    }
}

extern "C" void kernel_launch(void* const* d_in, const int* in_sizes, int n_in,
                              void* d_out, int out_size, void* d_ws, size_t ws_size,
                              hipStream_t stream) {
    const float* x    = (const float*)d_in[0];
    const float* Wih1 = (const float*)d_in[1];
    const float* Whh1 = (const float*)d_in[2];
    const float* bih1 = (const float*)d_in[3];
    const float* bhh1 = (const float*)d_in[4];
    const float* Wih2 = (const float*)d_in[5];
    const float* Whh2 = (const float*)d_in[6];
    const float* bih2 = (const float*)d_in[7];
    const float* bhh2 = (const float*)d_in[8];
    const float* Wlin = (const float*)d_in[9];
    const float* blin = (const float*)d_in[10];
    float* out = (float*)d_out;

    dim3 grid(256), block(192);
    hipLaunchKernelGGL(gru2_mfma, grid, block, 0, stream,
                       x, Wih1, Whh1, bih1, bhh1, Wih2, Whh2, bih2, bhh2,
                       Wlin, blin, out);
}